// Round 3
// baseline (95.191 us; speedup 1.0000x reference)
//
#include <hip/hip_runtime.h>

// probs [N,T,K] f32, targets [N,L] int32 (harness converts integer inputs)
constexpr int N_ = 32;
constexpr int T_ = 256;
constexpr int K_ = 8000;
constexpr int L_ = 64;
constexpr int NBLK = N_ * L_;   // 2048 blocks, one per (n,l) column

// Tiny init kernel: zero the ticket counter. NOT hipMemsetAsync — a 4-byte
// memset node in the captured graph cost ~77 us/replay (R1 post-mortem).
__global__ void ACE_zero_counter(unsigned int* counter) {
    *counter = 0u;
}

// Fused: per-block column sum + -log -> partial[bid]; the block that draws
// the last ticket (2047) reduces all partials and writes the scalar output.
__global__ __launch_bounds__(256) void ACE_fused(
    const float* __restrict__ probs,
    const int* __restrict__ targets,
    float* __restrict__ partial,          // [NBLK]
    unsigned int* __restrict__ counter,   // zeroed by ACE_zero_counter
    float* __restrict__ out) {
    const int bid = blockIdx.x;           // == n*L + l
    const int n = bid >> 6;               // L == 64
    const int t = threadIdx.x;            // 0..255 == time step

    const int k = targets[bid];
    const size_t idx = ((size_t)(n * T_ + t)) * (size_t)K_ + (size_t)k;
    float v = probs[idx];

    // 64-lane wave reduce
    #pragma unroll
    for (int off = 32; off > 0; off >>= 1)
        v += __shfl_down(v, off, 64);

    __shared__ float wsum[4];
    __shared__ bool is_last;
    if ((t & 63) == 0) wsum[t >> 6] = v;
    __syncthreads();

    if (t == 0) {
        const float s = wsum[0] + wsum[1] + wsum[2] + wsum[3];
        const float meanp = s * (1.0f / (float)T_) + 1e-10f;
        // release store, then acq_rel ticket: the block that sees ticket 2047
        // is last in modification order -> all 2047 other partial stores are
        // visible to its subsequent agent-scope loads.
        __hip_atomic_store(&partial[bid], -logf(meanp),
                           __ATOMIC_RELEASE, __HIP_MEMORY_SCOPE_AGENT);
        const unsigned int ticket = __hip_atomic_fetch_add(
            counter, 1u, __ATOMIC_ACQ_REL, __HIP_MEMORY_SCOPE_AGENT);
        is_last = (ticket == (unsigned int)(NBLK - 1));
    }
    __syncthreads();

    if (is_last) {
        float s = 0.0f;
        #pragma unroll
        for (int j = 0; j < NBLK / 256; ++j) {
            s += __hip_atomic_load(&partial[t + j * 256], __ATOMIC_RELAXED,
                                   __HIP_MEMORY_SCOPE_AGENT);
        }
        #pragma unroll
        for (int off = 32; off > 0; off >>= 1)
            s += __shfl_down(s, off, 64);
        if ((t & 63) == 0) wsum[t >> 6] = s;
        __syncthreads();
        if (t == 0) {
            const float total = wsum[0] + wsum[1] + wsum[2] + wsum[3];
            out[0] = total * (1.0f / ((float)N_ * (float)T_));
        }
    }
}

extern "C" void kernel_launch(void* const* d_in, const int* in_sizes, int n_in,
                              void* d_out, int out_size, void* d_ws, size_t ws_size,
                              hipStream_t stream) {
    const float* probs = (const float*)d_in[0];
    const int* targets = (const int*)d_in[1];
    float* out = (float*)d_out;

    unsigned int* counter = (unsigned int*)d_ws;          // 4 bytes
    float* partial = (float*)((char*)d_ws + 256);         // NBLK floats

    ACE_zero_counter<<<1, 1, 0, stream>>>(counter);
    ACE_fused<<<NBLK, 256, 0, stream>>>(probs, targets, partial, counter, out);
}

// Round 4
// 17.918 us; speedup vs baseline: 5.3125x; 5.3125x over previous
//
#include <hip/hip_runtime.h>

// probs [N,T,K] f32, targets [N,L] int32
constexpr int N_ = 32;
constexpr int T_ = 256;
constexpr int K_ = 8000;
constexpr int L_ = 64;
constexpr int NCOL = N_ * L_;               // 2048 (n,l) columns
constexpr int COLS_PER_BLK = 4;             // one column per wave
constexpr int NBLK1 = NCOL / COLS_PER_BLK;  // 512 blocks

// Kernel 1: one wave per (n,l) column. Lane loads 4 time-rows (independent
// gathers), wave butterfly-reduces, lane 0 writes -log(mean + 1e-10).
// No LDS, no __syncthreads, no atomics (R2: agent-scope atomics cost ~77us
// in cache maintenance on gfx950 — never again for this pattern).
__global__ __launch_bounds__(256) void ACE_colsum(
    const float* __restrict__ probs,
    const int* __restrict__ targets,
    float* __restrict__ partial) {
    const int w = threadIdx.x >> 6;
    const int lane = threadIdx.x & 63;
    const int c = blockIdx.x * COLS_PER_BLK + w;   // column id = n*L + l
    const int n = c >> 6;                          // L == 64
    const int k = targets[c];

    const size_t row0 = (size_t)(n * T_ + lane * 4);
    const float* p = probs + row0 * (size_t)K_ + (size_t)k;
    const float v0 = p[0];
    const float v1 = p[(size_t)K_];
    const float v2 = p[2 * (size_t)K_];
    const float v3 = p[3 * (size_t)K_];
    float v = (v0 + v1) + (v2 + v3);

    #pragma unroll
    for (int off = 32; off > 0; off >>= 1)
        v += __shfl_down(v, off, 64);

    if (lane == 0)
        partial[c] = -logf(v * (1.0f / (float)T_) + 1e-10f);
}

// Kernel 2: single wave reduces the 2048 partials (L2-hot) via float4 loads.
__global__ __launch_bounds__(64) void ACE_reduce(
    const float* __restrict__ partial,
    float* __restrict__ out) {
    const int t = threadIdx.x;                 // 0..63
    const float4* p4 = (const float4*)partial; // 512 float4s
    float s = 0.0f;
    #pragma unroll
    for (int j = 0; j < 8; ++j) {
        const float4 v = p4[t + j * 64];
        s += (v.x + v.y) + (v.z + v.w);
    }
    #pragma unroll
    for (int off = 32; off > 0; off >>= 1)
        s += __shfl_down(s, off, 64);
    if (t == 0)
        out[0] = s * (1.0f / ((float)N_ * (float)T_));
}

extern "C" void kernel_launch(void* const* d_in, const int* in_sizes, int n_in,
                              void* d_out, int out_size, void* d_ws, size_t ws_size,
                              hipStream_t stream) {
    const float* probs = (const float*)d_in[0];
    const int* targets = (const int*)d_in[1];
    float* out = (float*)d_out;
    float* partial = (float*)d_ws;             // NCOL floats = 8 KB

    ACE_colsum<<<NBLK1, 256, 0, stream>>>(probs, targets, partial);
    ACE_reduce<<<1, 64, 0, stream>>>(partial, out);
}